// Round 8
// baseline (129.276 us; speedup 1.0000x reference)
//
#include <hip/hip_runtime.h>
#include <hip/hip_bf16.h>
#include <math.h>

// Problem shape (fixed by setup_inputs): B=128, S=20, C=32000
#define NB 128
#define NS 20
#define NC 32000
#define RPB 2                         // LSE rows per block
#define NLSE (NB * NS / RPB)          // 1280 LSE blocks
#define NBLOCKS (NB + NLSE)           // 1408 total: all co-resident, one phase

// min with lane^1 / lane^2 via DPP quad_perm (pure VALU, no LDS)
static __device__ __forceinline__ float fmin_x1(float x) {
    int t = __builtin_amdgcn_update_dpp(0, __float_as_int(x), 0xB1, 0xf, 0xf, true); // [1,0,3,2]
    return fminf(x, __int_as_float(t));
}
static __device__ __forceinline__ float fmin_x2(float x) {
    int t = __builtin_amdgcn_update_dpp(0, __float_as_int(x), 0x4E, 0xf, 0xf, true); // [2,3,0,1]
    return fminf(x, __int_as_float(t));
}
// min with lane^4 / ^8 / ^16 via ds_swizzle bitmode (1 LDS-pipe op each)
static __device__ __forceinline__ float fmin_x4(float x) {
    int t = __builtin_amdgcn_ds_swizzle(__float_as_int(x), 0x101F);
    return fminf(x, __int_as_float(t));
}
static __device__ __forceinline__ float fmin_x8(float x) {
    int t = __builtin_amdgcn_ds_swizzle(__float_as_int(x), 0x201F);
    return fminf(x, __int_as_float(t));
}
static __device__ __forceinline__ float fmin_x16(float x) {
    int t = __builtin_amdgcn_ds_swizzle(__float_as_int(x), 0x401F);
    return fminf(x, __int_as_float(t));
}
static __device__ __forceinline__ float readlane_f(float x, int lane) {
    return __int_as_float(__builtin_amdgcn_readlane(__float_as_int(x), lane));
}
// targeted device-scope atomics (memory-side coherent; NO bulk L2 writeback)
static __device__ __forceinline__ void astore_f(float* p, float v) {
    __hip_atomic_store(p, v, __ATOMIC_RELAXED, __HIP_MEMORY_SCOPE_AGENT);
}
static __device__ __forceinline__ float aload_f(const float* p) {
    return __hip_atomic_load(p, __ATOMIC_RELAXED, __HIP_MEMORY_SCOPE_AGENT);
}

// ---------------------------------------------------------------------------
// One mega kernel, heterogeneous blocks + last-block-done combiner.
//   blockIdx.x <  NB : fused gather + restricted-softmax cost + wave-parallel
//                      Hungarian; per-row {w*x_match, w_match} atomic-stored.
//   blockIdx.x >= NB : two per-row logsumexps over C=32000; logZ atomic-stored.
// Every block ends with fetch_add(counter, ACQ_REL, AGENT); the last block
// combines via relaxed atomic loads (release sequence on the counter makes
// all prior atomic stores visible) — NO __threadfence, so no L2 writeback
// storms (round-6 failure mode).
// ---------------------------------------------------------------------------
__global__ __launch_bounds__(256) void mega_kernel(
        const float* __restrict__ outputs,
        const int* __restrict__ gold,
        const float* __restrict__ weight,
        const unsigned char* __restrict__ mask,
        unsigned* __restrict__ counter,  // zeroed via hipMemsetAsync pre-launch
        float* __restrict__ wx_arr,      // [NB*NS] w_match * x_match per row
        float* __restrict__ wm_arr,      // [NB*NS] w_match per row
        float* __restrict__ logZ,        // [NB*NS]
        float* __restrict__ out) {

    __shared__ float smx[4], ssm[4];
    __shared__ double sn[4], sm[4];
    __shared__ int    is_last;

    if (blockIdx.x < NB) {
        // =================== fused cost + wave Hungarian ===================
        const int b = blockIdx.x;
        const int* g = gold + b * NS;
        __shared__ float xraw[NS * NS];  // raw gathered logits (kept for epilogue)
        __shared__ float cst[NS * NS];   // cost matrix
        __shared__ float lzs[NS];

        // phase 1: gather outputs[b, i, gold[b, j]]
        for (int e = threadIdx.x; e < NS * NS; e += 256) {
            int i = e / NS, j = e - i * NS;
            xraw[e] = outputs[(size_t)(b * NS + i) * NC + g[j]];
        }
        __syncthreads();
        // phase 2: per-row restricted logsumexp over the 20 gold columns
        if (threadIdx.x < NS) {
            int i = threadIdx.x;
            float mx = xraw[i * NS];
#pragma unroll
            for (int j = 1; j < NS; ++j) mx = fmaxf(mx, xraw[i * NS + j]);
            float s = 0.f;
#pragma unroll
            for (int j = 0; j < NS; ++j) s += __expf(xraw[i * NS + j] - mx);
            lzs[i] = mx + __logf(s);
        }
        __syncthreads();
        // phase 3: cost = -(x - lz) * w[gold[j]]  (BIG replaces inf)
        for (int e = threadIdx.x; e < NS * NS; e += 256) {
            int i = e / NS, j = e - i * NS;
            float c = -(xraw[e] - lzs[i]) * weight[g[j]];
            if (isinf(c)) c = 1e8f;
            cst[e] = c;
        }
        __syncthreads();

        if (threadIdx.x < 64) {
            // ---- wave 0: shortest-augmenting-path Hungarian, f32 ----
            // Lane j (1..20) owns column j; p_j: matched row (0=free);
            // up_j = u[p_j]; lane 0 carries the phase row i / u[i].
            const int lane = threadIdx.x;
            const float FINF = INFINITY;
            float up_j = 0.f, v_j = 0.f;
            int p_j = 0, way_j = 0;
            const bool is_col = (lane >= 1 && lane <= NS);

            for (int i = 1; i <= NS; ++i) {
                if (lane == 0) { p_j = i; up_j = 0.f; }
                int j0 = 0;
                float minv_j = FINF;
                bool used_j = false;
                while (true) {
                    int pp = __builtin_amdgcn_readlane(p_j, j0);   // p[j0], uniform
                    if (pp == 0) break;            // free column reached
                    if (lane == j0) used_j = true;
                    float upp = readlane_f(up_j, j0);              // u[p[j0]]
                    float cv = cst[is_col ? (pp - 1) * NS + (lane - 1) : 0];
                    if (is_col && !used_j) {
                        float cur = cv - upp - v_j;
                        if (cur < minv_j) { minv_j = cur; way_j = j0; }  // strict <
                    }
                    float cand = (is_col && !used_j) ? minv_j : FINF;
                    float mval = fmin_x16(fmin_x8(fmin_x4(fmin_x2(fmin_x1(cand)))));
                    unsigned long long bal = __ballot(cand == mval) & 0xFFFFFFFFull;
                    int j1 = __ffsll(bal) - 1;     // lowest-lane = np.argmin tie-break
                    float delta = mval;
                    if (used_j) { up_j += delta; v_j -= delta; }
                    else if (is_col) minv_j -= delta;
                    j0 = j1;
                }
                while (j0 != 0) {                  // augment along way[]
                    int   j1   = __builtin_amdgcn_readlane(way_j, j0);
                    int   pj1  = __builtin_amdgcn_readlane(p_j, j1);
                    float upj1 = readlane_f(up_j, j1);
                    if (lane == j0) { p_j = pj1; up_j = upj1; }
                    j0 = j1;
                }
            }
            // epilogue: row p_j-1 matched to col j-1 -> store w*x and w
            if (is_col) {   // n==m -> every column matched, covers all rows
                int r = b * NS + (p_j - 1);
                float w = weight[g[lane - 1]];
                float x = xraw[(p_j - 1) * NS + (lane - 1)];
                astore_f(&wx_arr[r], w * x);
                astore_f(&wm_arr[r], w);
            }
        }
    } else {
        // =================== per-row logZ over C, RPB rows/block ===========
        const int rbase = (blockIdx.x - NB) * RPB;
        for (int rr = 0; rr < RPB; ++rr) {
            const int row = rbase + rr;
            const float4* rp = (const float4*)(outputs + (size_t)row * NC);
            const int n4 = NC / 4;   // 8000

            float m = -INFINITY;
            float s = 0.f;
            for (int idx = threadIdx.x; idx < n4; idx += blockDim.x) {
                float4 x = rp[idx];
                float m4 = fmaxf(fmaxf(x.x, x.y), fmaxf(x.z, x.w));
                float nm = fmaxf(m, m4);
                s = s * __expf(m - nm)
                  + __expf(x.x - nm) + __expf(x.y - nm)
                  + __expf(x.z - nm) + __expf(x.w - nm);
                m = nm;
            }
            for (int off = 1; off < 64; off <<= 1) {
                float om = __shfl_xor(m, off);
                float os = __shfl_xor(s, off);
                float nm = fmaxf(m, om);
                s = s * __expf(m - nm) + os * __expf(om - nm);
                m = nm;
            }
            __syncthreads();   // protect smx/ssm reuse across rr iterations
            int wid = threadIdx.x >> 6;
            if ((threadIdx.x & 63) == 0) { smx[wid] = m; ssm[wid] = s; }
            __syncthreads();
            if (threadIdx.x == 0) {
                float M = smx[0], S = ssm[0];
                for (int w = 1; w < 4; ++w) {
                    float om = smx[w], os = ssm[w];
                    float nm = fmaxf(M, om);
                    S = S * __expf(M - nm) + os * __expf(om - nm);
                    M = nm;
                }
                astore_f(&logZ[row], M + __logf(S));
            }
        }
    }

    // =================== last-block-done combiner ===================
    __syncthreads();
    if (threadIdx.x == 0) {
        unsigned prev = __hip_atomic_fetch_add(counter, 1u, __ATOMIC_ACQ_REL,
                                               __HIP_MEMORY_SCOPE_AGENT);
        is_last = (prev == (unsigned)(NBLOCKS - 1)) ? 1 : 0;
    }
    __syncthreads();
    if (is_last) {
        // all blocks' atomic stores are visible (release sequence on counter)
        double nsum = 0.0, msum = 0.0;
        for (int r = threadIdx.x; r < NB * NS; r += 256) {
            float wx = aload_f(&wx_arr[r]);
            float wm = aload_f(&wm_arr[r]);
            float lz = aload_f(&logZ[r]);
            float nll = wm * lz - wx;            // = -(x - logZ) * w
            float mk = mask[r] ? 1.f : 0.f;
            nsum += (double)(nll * mk);
            msum += (double)mk;
        }
        for (int off = 1; off < 64; off <<= 1) {
            nsum += __shfl_xor(nsum, off);
            msum += __shfl_xor(msum, off);
        }
        int wid = threadIdx.x >> 6;
        if ((threadIdx.x & 63) == 0) { sn[wid] = nsum; sm[wid] = msum; }
        __syncthreads();
        if (threadIdx.x == 0) {
            double N = 0.0, M = 0.0;
            for (int w = 0; w < 4; ++w) { N += sn[w]; M += sm[w]; }
            out[0] = (float)(N / (M + 1e-8));
        }
    }
}

// ---------------------------------------------------------------------------
extern "C" void kernel_launch(void* const* d_in, const int* in_sizes, int n_in,
                              void* d_out, int out_size, void* d_ws, size_t ws_size,
                              hipStream_t stream) {
    const float* outputs        = (const float*)d_in[0];          // [B,S,C] f32
    const int*   gold           = (const int*)d_in[1];            // [B,S] i32
    const unsigned char* mask   = (const unsigned char*)d_in[2];  // [B,S] bool
    const float* weight         = (const float*)d_in[3];          // [C] f32
    float* out = (float*)d_out;

    // workspace layout
    char* ws = (char*)d_ws;
    unsigned* counter = (unsigned*)ws;                                 // 16 B slot
    float* wx_arr = (float*)(ws + 16);                                 // NB*NS
    float* wm_arr = (float*)(ws + 16 + (size_t)NB * NS * 4);           // NB*NS
    float* logZ   = (float*)(ws + 16 + (size_t)NB * NS * 8);           // NB*NS

    hipMemsetAsync(counter, 0, sizeof(unsigned), stream);
    mega_kernel<<<NBLOCKS, 256, 0, stream>>>(outputs, gold, weight, mask,
                                             counter, wx_arr, wm_arr, logZ, out);
}

// Round 9
// 69.764 us; speedup vs baseline: 1.8531x; 1.8531x over previous
//
#include <hip/hip_runtime.h>
#include <hip/hip_bf16.h>
#include <math.h>

// Problem shape (fixed by setup_inputs): B=128, S=20, C=32000
#define NB 128
#define NS 20
#define NC 32000
#define RPB 2                         // LSE rows per block
#define NLSE (NB * NS / RPB)          // 1280 LSE blocks
#define NBLOCKS (NB + NLSE)           // 1408 total: all co-resident, one phase

// min with lane^1 / lane^2 via DPP quad_perm (pure VALU, no LDS)
static __device__ __forceinline__ float fmin_x1(float x) {
    int t = __builtin_amdgcn_update_dpp(0, __float_as_int(x), 0xB1, 0xf, 0xf, true); // [1,0,3,2]
    return fminf(x, __int_as_float(t));
}
static __device__ __forceinline__ float fmin_x2(float x) {
    int t = __builtin_amdgcn_update_dpp(0, __float_as_int(x), 0x4E, 0xf, 0xf, true); // [2,3,0,1]
    return fminf(x, __int_as_float(t));
}
// min with lane^4 / ^8 / ^16 via ds_swizzle bitmode (1 LDS-pipe op each)
static __device__ __forceinline__ float fmin_x4(float x) {
    int t = __builtin_amdgcn_ds_swizzle(__float_as_int(x), 0x101F);
    return fminf(x, __int_as_float(t));
}
static __device__ __forceinline__ float fmin_x8(float x) {
    int t = __builtin_amdgcn_ds_swizzle(__float_as_int(x), 0x201F);
    return fminf(x, __int_as_float(t));
}
static __device__ __forceinline__ float fmin_x16(float x) {
    int t = __builtin_amdgcn_ds_swizzle(__float_as_int(x), 0x401F);
    return fminf(x, __int_as_float(t));
}
static __device__ __forceinline__ float readlane_f(float x, int lane) {
    return __int_as_float(__builtin_amdgcn_readlane(__float_as_int(x), lane));
}

// ---------------------------------------------------------------------------
// Mega kernel, heterogeneous blocks. NO cross-block sync of any kind —
// fences (r6) and acq/rel atomics (r8) both trigger per-block L2
// writeback/invalidate storms on gfx950 that destroy the HBM stream.
//   blockIdx.x <  NB : fused gather + restricted-softmax cost + wave-parallel
//                      Hungarian (readlane + DPP/swizzle min butterfly).
//   blockIdx.x >= NB : two per-row logsumexps over C=32000, 4-deep unrolled
//                      loads for 4x memory-level parallelism (latency-bound
//                      fix: 1 outstanding load/thread -> 4).
// ---------------------------------------------------------------------------
__global__ __launch_bounds__(256) void mega_kernel(
        const float* __restrict__ outputs,
        const int* __restrict__ gold,
        const float* __restrict__ weight,
        int* __restrict__ match_col,     // [NB*NS] assigned 0-based column per row
        float* __restrict__ sub_ws,      // [NB*NS*NS] raw gathered logits
        float* __restrict__ logZ) {      // [NB*NS]

    if (blockIdx.x < NB) {
        // =================== fused cost + wave Hungarian ===================
        const int b = blockIdx.x;
        const int* g = gold + b * NS;
        __shared__ float cst[NS * NS];   // sub logits, then cost, in place
        __shared__ float lzs[NS];

        // phase 1: gather outputs[b, i, gold[b, j]] + save raw logits to ws
        for (int e = threadIdx.x; e < NS * NS; e += 256) {
            int i = e / NS, j = e - i * NS;
            float x = outputs[(size_t)(b * NS + i) * NC + g[j]];
            cst[e] = x;
            sub_ws[(size_t)(b * NS + i) * NS + j] = x;
        }
        __syncthreads();
        // phase 2: per-row restricted logsumexp over the 20 gold columns
        if (threadIdx.x < NS) {
            int i = threadIdx.x;
            float mx = cst[i * NS];
#pragma unroll
            for (int j = 1; j < NS; ++j) mx = fmaxf(mx, cst[i * NS + j]);
            float s = 0.f;
#pragma unroll
            for (int j = 0; j < NS; ++j) s += __expf(cst[i * NS + j] - mx);
            lzs[i] = mx + __logf(s);
        }
        __syncthreads();
        // phase 3: cost = -(x - lz) * w[gold[j]]  (BIG replaces inf)
        for (int e = threadIdx.x; e < NS * NS; e += 256) {
            int i = e / NS, j = e - i * NS;
            float c = -(cst[e] - lzs[i]) * weight[g[j]];
            if (isinf(c)) c = 1e8f;
            cst[e] = c;
        }
        __syncthreads();
        if (threadIdx.x >= 64) return;   // waves 1..3 done

        // ---- wave 0: shortest-augmenting-path Hungarian, f32 potentials ----
        // Lane j (1..20) owns column j: p_j matched row (0=free), up_j=u[p_j],
        // v_j col potential; lane 0 carries phase row i / u[i].
        const int lane = threadIdx.x;
        const float FINF = INFINITY;
        float up_j = 0.f, v_j = 0.f;
        int p_j = 0, way_j = 0;
        const bool is_col = (lane >= 1 && lane <= NS);

        for (int i = 1; i <= NS; ++i) {
            if (lane == 0) { p_j = i; up_j = 0.f; }   // p[0]=i, u[i]=0
            int j0 = 0;
            float minv_j = FINF;
            bool used_j = false;
            while (true) {
                int pp = __builtin_amdgcn_readlane(p_j, j0);   // p[j0], uniform
                if (pp == 0) break;           // free column reached
                if (lane == j0) used_j = true;
                float upp = readlane_f(up_j, j0);              // u[p[j0]], uniform
                float cv = cst[is_col ? (pp - 1) * NS + (lane - 1) : 0];
                if (is_col && !used_j) {
                    float cur = cv - upp - v_j;
                    if (cur < minv_j) { minv_j = cur; way_j = j0; }  // strict <
                }
                float cand = (is_col && !used_j) ? minv_j : FINF;
                // 5-step min over lanes 0..31: 2 DPP + 3 swizzle
                float mval = fmin_x16(fmin_x8(fmin_x4(fmin_x2(fmin_x1(cand)))));
                // lowest-lane argmin (np.argmin tie-break); mask off lanes>=32
                unsigned long long bal = __ballot(cand == mval) & 0xFFFFFFFFull;
                int j1 = __ffsll(bal) - 1;
                float delta = mval;           // uniform on lanes 0..31
                if (used_j) { up_j += delta; v_j -= delta; } // u[p[used]]+=d, v[used]-=d
                else if (is_col) minv_j -= delta;            // minv[~used]-=d
                j0 = j1;
            }
            // augment along way[] chain (j0 = free column)
            while (j0 != 0) {
                int   j1   = __builtin_amdgcn_readlane(way_j, j0);
                int   pj1  = __builtin_amdgcn_readlane(p_j, j1);
                float upj1 = readlane_f(up_j, j1);
                if (lane == j0) { p_j = pj1; up_j = upj1; }
                j0 = j1;
            }
        }
        // ans[p[j]-1] = j-1
        if (is_col && p_j != 0) {
            match_col[b * NS + (p_j - 1)] = lane - 1;
        }
    } else {
        // =================== per-row logZ over C, RPB rows/block ===========
        __shared__ float smx[4], ssm[4];
        const int rbase = (blockIdx.x - NB) * RPB;
        for (int rr = 0; rr < RPB; ++rr) {
            const int row = rbase + rr;
            const float4* rp = (const float4*)(outputs + (size_t)row * NC);
            const int n4 = NC / 4;            // 8000
            const int nfull = (n4 / 1024) * 1024;   // 7168: 4-deep unrolled region

            float m = -INFINITY;
            float s = 0.f;
            // 4 independent coalesced loads in flight per thread (MLP fix)
            for (int base = 0; base < nfull; base += 1024) {
                int i0 = base + threadIdx.x;
                float4 a = rp[i0];
                float4 bq = rp[i0 + 256];
                float4 c = rp[i0 + 512];
                float4 d = rp[i0 + 768];
                float m4 = fmaxf(fmaxf(fmaxf(a.x, a.y), fmaxf(a.z, a.w)),
                                 fmaxf(fmaxf(bq.x, bq.y), fmaxf(bq.z, bq.w)));
                m4 = fmaxf(m4, fmaxf(fmaxf(fmaxf(c.x, c.y), fmaxf(c.z, c.w)),
                                     fmaxf(fmaxf(d.x, d.y), fmaxf(d.z, d.w))));
                float nm = fmaxf(m, m4);
                float sl = __expf(a.x - nm) + __expf(a.y - nm)
                         + __expf(a.z - nm) + __expf(a.w - nm);
                sl += __expf(bq.x - nm) + __expf(bq.y - nm)
                    + __expf(bq.z - nm) + __expf(bq.w - nm);
                sl += __expf(c.x - nm) + __expf(c.y - nm)
                    + __expf(c.z - nm) + __expf(c.w - nm);
                sl += __expf(d.x - nm) + __expf(d.y - nm)
                    + __expf(d.z - nm) + __expf(d.w - nm);
                s = s * __expf(m - nm) + sl;
                m = nm;
            }
            // remainder (832 float4s), single-load loop
            for (int idx = nfull + threadIdx.x; idx < n4; idx += 256) {
                float4 x = rp[idx];
                float m4 = fmaxf(fmaxf(x.x, x.y), fmaxf(x.z, x.w));
                float nm = fmaxf(m, m4);
                s = s * __expf(m - nm)
                  + __expf(x.x - nm) + __expf(x.y - nm)
                  + __expf(x.z - nm) + __expf(x.w - nm);
                m = nm;
            }
            for (int off = 1; off < 64; off <<= 1) {
                float om = __shfl_xor(m, off);
                float os = __shfl_xor(s, off);
                float nm = fmaxf(m, om);
                s = s * __expf(m - nm) + os * __expf(om - nm);
                m = nm;
            }
            __syncthreads();   // protect smx/ssm reuse across rr iterations
            int wid = threadIdx.x >> 6;
            if ((threadIdx.x & 63) == 0) { smx[wid] = m; ssm[wid] = s; }
            __syncthreads();
            if (threadIdx.x == 0) {
                float M = smx[0], S = ssm[0];
                for (int w = 1; w < 4; ++w) {
                    float om = smx[w], os = ssm[w];
                    float nm = fmaxf(M, om);
                    S = S * __expf(M - nm) + os * __expf(om - nm);
                    M = nm;
                }
                logZ[row] = M + __logf(S);
            }
        }
    }
}

// ---------------------------------------------------------------------------
// Final masked-mean NLL reduce — everything L2-hot (sub_ws, logZ, match_col).
// Deterministic tree reduce, f64 accumulation.
// ---------------------------------------------------------------------------
__global__ __launch_bounds__(256) void final_kernel(
        const int* __restrict__ match_col,
        const float* __restrict__ sub_ws,
        const float* __restrict__ logZ,
        const float* __restrict__ weight,
        const int* __restrict__ gold,
        const unsigned char* __restrict__ mask,
        float* __restrict__ out) {
    double nsum = 0.0, msum = 0.0;
    for (int r = threadIdx.x; r < NB * NS; r += 256) {
        int b = r / NS;
        int col = match_col[r];
        float x = sub_ws[(size_t)r * NS + col];          // outputs[b,i,match]
        float w = weight[gold[b * NS + col]];            // weight[match]
        float nll = -(x - logZ[r]) * w;
        float mk = mask[r] ? 1.f : 0.f;
        nsum += (double)(nll * mk);
        msum += (double)mk;
    }
    for (int off = 1; off < 64; off <<= 1) {
        nsum += __shfl_xor(nsum, off);
        msum += __shfl_xor(msum, off);
    }
    __shared__ double sn[4], sm[4];
    int wid = threadIdx.x >> 6;
    if ((threadIdx.x & 63) == 0) { sn[wid] = nsum; sm[wid] = msum; }
    __syncthreads();
    if (threadIdx.x == 0) {
        double N = 0.0, M = 0.0;
        for (int w = 0; w < 4; ++w) { N += sn[w]; M += sm[w]; }
        out[0] = (float)(N / (M + 1e-8));
    }
}

// ---------------------------------------------------------------------------
extern "C" void kernel_launch(void* const* d_in, const int* in_sizes, int n_in,
                              void* d_out, int out_size, void* d_ws, size_t ws_size,
                              hipStream_t stream) {
    const float* outputs        = (const float*)d_in[0];          // [B,S,C] f32
    const int*   gold           = (const int*)d_in[1];            // [B,S] i32
    const unsigned char* mask   = (const unsigned char*)d_in[2];  // [B,S] bool
    const float* weight         = (const float*)d_in[3];          // [C] f32
    float* out = (float*)d_out;

    // workspace layout
    char* ws = (char*)d_ws;
    int*   match_col = (int*)ws;                                   // NB*NS
    float* logZ      = (float*)(ws + (size_t)NB * NS * 4);         // NB*NS
    float* sub_ws    = (float*)(ws + (size_t)NB * NS * 8);         // NB*NS*NS

    mega_kernel<<<NBLOCKS, 256, 0, stream>>>(outputs, gold, weight,
                                             match_col, sub_ws, logZ);
    final_kernel<<<1, 256, 0, stream>>>(match_col, sub_ws, logZ, weight, gold,
                                        mask, out);
}